// Round 17
// baseline (45.077 us; speedup 1.0000x reference)
//
#include <hip/hip_runtime.h>

#define BB 4
#define CC 64
#define HH 128
#define WW 128
#define OO 64
#define HWs (HH*WW)
#define R9 9
#define XW 36

typedef _Float16 f16;
typedef _Float16 f16x8 __attribute__((ext_vector_type(8)));
typedef _Float16 f16x2 __attribute__((ext_vector_type(2)));
typedef float f32x16 __attribute__((ext_vector_type(16)));

__device__ __forceinline__ size_t xt_idx(int b, int y, int x) {
    return (((size_t)b * HH + y) * WW + x) * CC;
}

// ---------- fused prep: x transpose (NCHW f32 -> NHWC f16) + weight packing ----------
// wA_off[ks(36)][l][8]            : A[m=l&31][k=ks*16+(l>>5)*8+i], m<18 valid (32x32x16)
// wA_def[(tap*4+ks2)*2+ot][l][8]  : A[m=ot*32+(l&31)][c=ks2*16+(l>>5)*8+i]
__global__ __launch_bounds__(256) void prep_all(const float* __restrict__ x,
                                                const float* __restrict__ offw,
                                                const float* __restrict__ dw,
                                                f16* __restrict__ xt,
                                                f16* __restrict__ wA_off,
                                                f16* __restrict__ wA_def) {
    const int bid = blockIdx.x;
    const int tid = threadIdx.x;
    if (bid < 512) {
        const int b = bid >> 7, y = bid & 127;
        const int px = tid & 127, half = tid >> 7;
        const float* src = x + (size_t)b * CC * HWs + (size_t)half * 32 * HWs + y * WW + px;
        f16* dst = xt + xt_idx(b, y, px) + half * 32;
        #pragma unroll
        for (int cg = 0; cg < 4; ++cg) {
            f16x8 v;
            #pragma unroll
            for (int j = 0; j < 8; ++j)
                v[j] = (f16)src[(size_t)(cg * 8 + j) * HWs];
            *(f16x8*)(dst + cg * 8) = v;
        }
    } else {
        const int t = (bid - 512) * 256 + tid;
        const int l = t & 63;
        const int idx = t >> 6;
        f16x8 v;
        if (idx < 36) {
            const int ks = idx;
            const int m = l & 31;
            #pragma unroll
            for (int i = 0; i < 8; ++i) {
                const int k = ks * 16 + (l >> 5) * 8 + i;
                const int tap = k >> 6, c = k & 63;
                const int ky = tap / 3, kx = tap % 3;
                v[i] = (m < 18) ? (f16)offw[((m * CC + c) * 3 + ky) * 3 + kx] : (f16)0.f;
            }
            *(f16x8*)(wA_off + (size_t)(idx * 64 + l) * 8) = v;
        } else if (idx < 108) {
            const int id2 = idx - 36;                  // (tap*4+ks2)*2+ot
            const int ot = id2 & 1, ks2 = (id2 >> 1) & 3, tap = id2 >> 3;
            const int m = ot * 32 + (l & 31);
            #pragma unroll
            for (int i = 0; i < 8; ++i) {
                const int c = ks2 * 16 + (l >> 5) * 8 + i;
                v[i] = (f16)dw[(size_t)(m * CC + c) * 9 + tap];
            }
            *(f16x8*)(wA_def + (size_t)(id2 * 64 + l) * 8) = v;
        }
    }
}

__device__ __forceinline__ f16x8 combine4(f16x8 p00, f16x8 p01, f16x8 p10, f16x8 p11,
                                          f16 h00, f16 h01, f16 h10, f16 h11) {
    const f16x8 W00 = {h00,h00,h00,h00,h00,h00,h00,h00};
    const f16x8 W01 = {h01,h01,h01,h01,h01,h01,h01,h01};
    const f16x8 W10 = {h10,h10,h10,h10,h10,h10,h10,h10};
    const f16x8 W11 = {h11,h11,h11,h11,h11,h11,h11,h11};
    return p00 * W00 + p01 * W01 + p10 * W10 + p11 * W11;
}

// ---------- main: 4-row x 32-px blocks, 32x32x16 MFMA (wave = 1 row x 32 px) ----------
__global__ __launch_bounds__(256, 3) void deform_mfma(
    const f16* __restrict__ xt,
    const f16* __restrict__ wA_off,
    const float* __restrict__ offb,
    const f16* __restrict__ wA_def,
    const float* __restrict__ dbias,
    float* __restrict__ out)
{
    // window [9 rows][36 cols][8 chunks of 16B], chunk slot XOR-swizzled: 41472 B
    __shared__ __align__(16) char win[R9 * XW * 8 * 16];
    __shared__ float offs[18][128];    // 4 rows x 32 px -> total 50688 B

    const int tid = threadIdx.x;
    const int bid0 = blockIdx.x;
    const int bid = (bid0 & 7) * 64 + (bid0 >> 3);    // XCD swizzle (512 % 8 == 0)
    const int b  = bid >> 7;               // 128 blocks per batch
    const int rg = (bid >> 2) & 31;
    const int pg = bid & 3;
    const int r0 = rg * 4, px0 = pg * 32;

    const int ri = tid >> 6, l = tid & 63;      // wave = row index
    const int n  = l & 31, kh = l >> 5;         // pixel-in-tile, k-half
    const int row = r0 + ri;
    const int gpx = px0 + n;
    const int slot = ri * 32 + n;               // 0..127

    // ---- stage window rows r0-2..r0+6, x in [px0-2, px0+33], zero-padded ----
    #pragma unroll
    for (int it = 0; it < 11; ++it) {
        const int i = tid + it * 256;
        if (i < R9 * XW * 8) {
            const int s = i / (XW * 8), rem = i - s * (XW * 8);
            const int xw = rem >> 3, ch8 = rem & 7;
            const int gy = r0 - 2 + s, gx = px0 - 2 + xw;
            f16x8 v = {};
            if (gy >= 0 && gy < HH && gx >= 0 && gx < WW)
                v = *(const f16x8*)(xt + xt_idx(b, gy, gx) + ch8 * 8);
            *(f16x8*)(win + ((s * XW + xw) * 8 + (ch8 ^ ((xw + s) & 7))) * 16) = v;
        }
    }
    __syncthreads();

    // ---- phase 1: offset conv, 36 K-steps of 32x32x16 (oc padded 18->32) ----
    {
        f32x16 oa = {0,0,0,0,0,0,0,0,0,0,0,0,0,0,0,0};
        #pragma unroll
        for (int ks = 0; ks < 36; ++ks) {
            const int tap = ks >> 2;               // 4 K-steps per tap
            const int ky = tap / 3, kx = tap - ky * 3;
            const int s = ri + 1 + ky;             // [1,6]
            const int xw = n + 1 + kx;             // [1,34]
            const int ch8 = (ks & 3) * 2 + kh;
            const f16x8 bf = *(const f16x8*)(win + ((s * XW + xw) * 8 + (ch8 ^ ((xw + s) & 7))) * 16);
            const f16x8 a = *(const f16x8*)(wA_off + (size_t)(ks * 64 + l) * 8);
            oa = __builtin_amdgcn_mfma_f32_32x32x16_f16(a, bf, oa, 0, 0, 0);
        }
        #pragma unroll
        for (int reg = 0; reg < 16; ++reg) {
            const int ch = (reg & 3) + 8 * (reg >> 2) + 4 * kh;
            if (ch < 18) offs[ch][slot] = oa[reg] + offb[ch];
        }
    }
    __syncthreads();   // offs final; win read-only from here

    // ---- tap precompute: per-lane pixel n; window covers full tap reach ----
    int o00[9], o01[9], o10[9], o11[9];
    f16x2 hA[9], hB[9];
    unsigned okm = 0;
    #pragma unroll
    for (int t = 0; t < 9; ++t) {
        const int ky = t / 3, kx = t - ky * 3;
        const float dy = offs[2 * t][slot], dx = offs[2 * t + 1][slot];
        const float py  = (float)(row - 1 + ky) + dy;
        const float pxf = (float)(gpx - 1 + kx) + dx;
        const float y0f = floorf(py), x0f = floorf(pxf);
        const float wy = py - y0f, wx = pxf - x0f;
        const int y0 = (int)y0f, x0 = (int)x0f;
        const int y1 = y0 + 1, x1 = x0 + 1;
        const bool vy0 = (y0 >= 0) & (y0 < HH), vy1 = (y1 >= 0) & (y1 < HH);
        const bool vx0 = (x0 >= 0) & (x0 < WW), vx1 = (x1 >= 0) & (x1 < WW);
        hA[t][0] = (f16)((1.f - wy) * (1.f - wx) * (float)(vy0 & vx0));
        hA[t][1] = (f16)((1.f - wy) * wx         * (float)(vy0 & vx1));
        hB[t][0] = (f16)(wy * (1.f - wx)         * (float)(vy1 & vx0));
        hB[t][1] = (f16)(wy * wx                 * (float)(vy1 & vx1));
        const int cy0 = min(max(y0, 0), HH - 1), cy1 = min(max(y1, 0), HH - 1);
        const int cx0 = min(max(x0, 0), WW - 1), cx1 = min(max(x1, 0), WW - 1);
        const int s0 = cy0 - (r0 - 2), s1 = cy1 - (r0 - 2);
        const int u0 = cx0 - (px0 - 2), u1 = cx1 - (px0 - 2);
        const int ok = (s0 >= 0) & (s0 < R9) & (s1 >= 0) & (s1 < R9) &
                       (u0 >= 0) & (u0 < XW) & (u1 >= 0) & (u1 < XW);
        if (__all(ok)) okm |= (1u << t);
        const int s0c = min(max(s0, 0), R9 - 1), s1c = min(max(s1, 0), R9 - 1);
        const int u0c = min(max(u0, 0), XW - 1), u1c = min(max(u1, 0), XW - 1);
        // base byte offsets for ks2=0 (chunk = kh); ks2 adds ^ (ks2<<5)
        o00[t] = ((s0c * XW + u0c) * 8 + (kh ^ ((u0c + s0c) & 7))) * 16;
        o01[t] = ((s0c * XW + u1c) * 8 + (kh ^ ((u1c + s0c) & 7))) * 16;
        o10[t] = ((s1c * XW + u0c) * 8 + (kh ^ ((u0c + s1c) & 7))) * 16;
        o11[t] = ((s1c * XW + u1c) * 8 + (kh ^ ((u1c + s1c) & 7))) * 16;
    }

    f32x16 acc0 = {0,0,0,0,0,0,0,0,0,0,0,0,0,0,0,0};
    f32x16 acc1 = {0,0,0,0,0,0,0,0,0,0,0,0,0,0,0,0};
    const f16* wbase = wA_def + (size_t)l * 8;

    if (okm == 0x1FFu) {
        // ---- FAST PATH: 36 branch-free clusters; 1 A-pair per cluster, 2 MFMA ----
        #pragma unroll
        for (int j = 0; j < 36; ++j) {
            const int t = j >> 2, fl = (j & 3) << 5;
            const f16x8 p00 = *(const f16x8*)(win + (o00[t] ^ fl));
            const f16x8 p01 = *(const f16x8*)(win + (o01[t] ^ fl));
            const f16x8 p10 = *(const f16x8*)(win + (o10[t] ^ fl));
            const f16x8 p11 = *(const f16x8*)(win + (o11[t] ^ fl));
            const f16x8 bf = combine4(p00, p01, p10, p11,
                                      hA[t][0], hA[t][1], hB[t][0], hB[t][1]);
            const f16* wa = wbase + (size_t)j * 1024;
            acc0 = __builtin_amdgcn_mfma_f32_32x32x16_f16(*(const f16x8*)(wa + 0 * 512), bf, acc0, 0, 0, 0);
            acc1 = __builtin_amdgcn_mfma_f32_32x32x16_f16(*(const f16x8*)(wa + 1 * 512), bf, acc1, 0, 0, 0);
        }
    } else {
        // ---- SLOW PATH: per-tap wave-uniform fallback to global gather ----
        #pragma unroll
        for (int t = 0; t < 9; ++t) {
            #pragma unroll
            for (int ks2 = 0; ks2 < 4; ++ks2) {
                const int fl = ks2 << 5;
                f16x8 bf;
                if ((okm >> t) & 1) {
                    const f16x8 p00 = *(const f16x8*)(win + (o00[t] ^ fl));
                    const f16x8 p01 = *(const f16x8*)(win + (o01[t] ^ fl));
                    const f16x8 p10 = *(const f16x8*)(win + (o10[t] ^ fl));
                    const f16x8 p11 = *(const f16x8*)(win + (o11[t] ^ fl));
                    bf = combine4(p00, p01, p10, p11,
                                  hA[t][0], hA[t][1], hB[t][0], hB[t][1]);
                } else {
                    const int ky = t / 3, kx = t - ky * 3;
                    const float dy = offs[2 * t][slot], dx = offs[2 * t + 1][slot];
                    const float py  = (float)(row - 1 + ky) + dy;
                    const float pxf = (float)(gpx - 1 + kx) + dx;
                    const int y0 = (int)floorf(py), x0 = (int)floorf(pxf);
                    const int cy0 = min(max(y0, 0), HH - 1), cy1 = min(max(y0 + 1, 0), HH - 1);
                    const int cx0 = min(max(x0, 0), WW - 1), cx1 = min(max(x0 + 1, 0), WW - 1);
                    const int cb = ks2 * 16 + kh * 8;
                    const f16x8 p00 = *(const f16x8*)(xt + xt_idx(b, cy0, cx0) + cb);
                    const f16x8 p01 = *(const f16x8*)(xt + xt_idx(b, cy0, cx1) + cb);
                    const f16x8 p10 = *(const f16x8*)(xt + xt_idx(b, cy1, cx0) + cb);
                    const f16x8 p11 = *(const f16x8*)(xt + xt_idx(b, cy1, cx1) + cb);
                    bf = combine4(p00, p01, p10, p11,
                                  hA[t][0], hA[t][1], hB[t][0], hB[t][1]);
                }
                const f16* wa = wbase + (size_t)(t * 4 + ks2) * 1024;
                acc0 = __builtin_amdgcn_mfma_f32_32x32x16_f16(*(const f16x8*)(wa + 0 * 512), bf, acc0, 0, 0, 0);
                acc1 = __builtin_amdgcn_mfma_f32_32x32x16_f16(*(const f16x8*)(wa + 1 * 512), bf, acc1, 0, 0, 0);
            }
        }
    }

    // ---- epilogue: C layout col=n, row=(reg&3)+8*(reg>>2)+4*kh ----
    #pragma unroll
    for (int reg = 0; reg < 16; ++reg) {
        const int oc = (reg & 3) + 8 * (reg >> 2) + 4 * kh;
        out[(((size_t)b * OO + oc) * HH + row) * WW + gpx]        = acc0[reg] + dbias[oc];
        out[(((size_t)b * OO + oc + 32) * HH + row) * WW + gpx]   = acc1[reg] + dbias[oc + 32];
    }
}

extern "C" void kernel_launch(void* const* d_in, const int* in_sizes, int n_in,
                              void* d_out, int out_size, void* d_ws, size_t ws_size,
                              hipStream_t stream) {
    const float* x     = (const float*)d_in[0];
    const float* offw  = (const float*)d_in[1];
    const float* offb  = (const float*)d_in[2];
    const float* dw    = (const float*)d_in[3];
    const float* dbias = (const float*)d_in[4];
    float* out = (float*)d_out;

    const size_t XT_BYTES    = (size_t)BB * HH * WW * CC * sizeof(f16);   // 8 MiB
    const size_t WAOFF_BYTES = 36 * 64 * 8 * sizeof(f16);

    f16* xt     = (f16*)d_ws;
    f16* wa_off = (f16*)((char*)d_ws + XT_BYTES);
    f16* wa_def = (f16*)((char*)d_ws + XT_BYTES + WAOFF_BYTES);
    (void)ws_size; (void)in_sizes; (void)n_in; (void)out_size;

    prep_all<<<512 + 27, 256, 0, stream>>>(x, offw, dw, xt, wa_off, wa_def);
    deform_mfma<<<512, 256, 0, stream>>>(xt, wa_off, offb, wa_def, dbias, out);
}

// Round 18
// 37.559 us; speedup vs baseline: 1.2002x; 1.2002x over previous
//
#include <hip/hip_runtime.h>

#define BB 4
#define CC 64
#define HH 128
#define WW 128
#define OO 64
#define HWs (HH*WW)
#define R9 9
#define XW 20

typedef _Float16 f16;
typedef _Float16 f16x8 __attribute__((ext_vector_type(8)));
typedef _Float16 f16x2 __attribute__((ext_vector_type(2)));
typedef float f32x4 __attribute__((ext_vector_type(4)));

__device__ __forceinline__ size_t xt_idx(int b, int y, int x) {
    return (((size_t)b * HH + y) * WW + x) * CC;
}

// ---------- fused prep: x transpose (NCHW f32 -> NHWC f16) + weight packing ----------
__global__ __launch_bounds__(256) void prep_all(const float* __restrict__ x,
                                                const float* __restrict__ offw,
                                                const float* __restrict__ dw,
                                                f16* __restrict__ xt,
                                                f16* __restrict__ wA_off,
                                                f16* __restrict__ wA_def) {
    const int bid = blockIdx.x;
    const int tid = threadIdx.x;
    if (bid < 512) {
        const int b = bid >> 7, y = bid & 127;
        const int px = tid & 127, half = tid >> 7;
        const float* src = x + (size_t)b * CC * HWs + (size_t)half * 32 * HWs + y * WW + px;
        f16* dst = xt + xt_idx(b, y, px) + half * 32;
        #pragma unroll
        for (int cg = 0; cg < 4; ++cg) {
            f16x8 v;
            #pragma unroll
            for (int j = 0; j < 8; ++j)
                v[j] = (f16)src[(size_t)(cg * 8 + j) * HWs];
            *(f16x8*)(dst + cg * 8) = v;
        }
    } else {
        const int t = (bid - 512) * 256 + tid;
        const int l = t & 63;
        const int idx = t >> 6;
        f16x8 v;
        if (idx < 36) {
            const int mt = idx & 1, ks = idx >> 1;
            const int o = mt * 16 + (l & 15);
            const int tap = ks >> 1, ky = tap / 3, kx = tap % 3;
            #pragma unroll
            for (int i = 0; i < 8; ++i) {
                const int c = (ks & 1) * 32 + (l >> 4) * 8 + i;
                v[i] = (o < 18) ? (f16)offw[((o * CC + c) * 3 + ky) * 3 + kx] : (f16)0.f;
            }
            *(f16x8*)(wA_off + (size_t)(idx * 64 + l) * 8) = v;
        } else if (idx < 108) {
            const int id2 = idx - 36;
            const int mt = id2 & 3, ks = (id2 >> 2) & 1, tap = id2 >> 3;
            const int o = mt * 16 + (l & 15);
            #pragma unroll
            for (int i = 0; i < 8; ++i) {
                const int c = ks * 32 + (l >> 4) * 8 + i;
                v[i] = (f16)dw[(size_t)(o * CC + c) * 9 + tap];
            }
            *(f16x8*)(wA_def + (size_t)(id2 * 64 + l) * 8) = v;
        }
    }
}

__device__ __forceinline__ f16x8 combine4(f16x8 p00, f16x8 p01, f16x8 p10, f16x8 p11,
                                          f16 h00, f16 h01, f16 h10, f16 h11) {
    const f16x8 W00 = {h00,h00,h00,h00,h00,h00,h00,h00};
    const f16x8 W01 = {h01,h01,h01,h01,h01,h01,h01,h01};
    const f16x8 W10 = {h10,h10,h10,h10,h10,h10,h10,h10};
    const f16x8 W11 = {h11,h11,h11,h11,h11,h11,h11,h11};
    return p00 * W00 + p01 * W01 + p10 * W10 + p11 * W11;
}

// ---------- main: 4-row x 16-px blocks; full residency; healthy register budget ----------
__global__ __launch_bounds__(256, 4) void deform_mfma(
    const f16* __restrict__ xt,
    const f16* __restrict__ wA_off,
    const float* __restrict__ offb,
    const f16* __restrict__ wA_def,
    const float* __restrict__ dbias,
    float* __restrict__ out)
{
    // window [9 rows][20 cols][8 chunks of 16B], chunk slot XOR-swizzled: 23040 B
    __shared__ __align__(16) char win[R9 * XW * 8 * 16];
    __shared__ float offs[18][64];     // 4 rows x 16 px -> 27648 B total

    const int tid = threadIdx.x;
    const int bid0 = blockIdx.x;
    const int bid = (bid0 & 7) * 128 + (bid0 >> 3);   // XCD swizzle (1024 % 8 == 0)
    const int b  = bid >> 8;               // 256 blocks per batch
    const int rg = (bid >> 3) & 31;
    const int pg = bid & 7;
    const int r0 = rg * 4, px0 = pg * 16;

    const int ri = tid >> 6, l = tid & 63;      // wave = row index
    const int pxs = l & 15, cg = l >> 4;
    const int row = r0 + ri;
    const int gpx = px0 + pxs;
    const int slot = ri * 16 + pxs;             // 0..63

    // ---- stage window rows r0-2..r0+6, x in [px0-2, px0+17], zero-padded ----
    #pragma unroll
    for (int it = 0; it < 6; ++it) {
        const int i = tid + it * 256;
        if (i < R9 * XW * 8) {
            const int s = i / (XW * 8), rem = i - s * (XW * 8);
            const int xw = rem >> 3, ch8 = rem & 7;
            const int gy = r0 - 2 + s, gx = px0 - 2 + xw;
            f16x8 v = {};
            if (gy >= 0 && gy < HH && gx >= 0 && gx < WW)
                v = *(const f16x8*)(xt + xt_idx(b, gy, gx) + ch8 * 8);
            *(f16x8*)(win + ((s * XW + xw) * 8 + (ch8 ^ ((xw + s) & 7))) * 16) = v;
        }
    }
    __syncthreads();

    // ---- phase 1: offset conv for this row's 16 px ----
    {
        f32x4 oa0 = {0,0,0,0}, oa1 = {0,0,0,0};
        #pragma unroll
        for (int ks = 0; ks < 18; ++ks) {
            const int tap = ks >> 1, chalf = ks & 1;
            const int ky = tap / 3, kx = tap - ky * 3;
            const int s = ri + 1 + ky;              // [1,6]
            const int xw = pxs + 1 + kx;            // [1,17]
            const int ch8 = chalf * 4 + cg;
            const f16x8 bf = *(const f16x8*)(win + ((s * XW + xw) * 8 + (ch8 ^ ((xw + s) & 7))) * 16);
            const f16x8 a0 = *(const f16x8*)(wA_off + (size_t)((ks * 2 + 0) * 64 + l) * 8);
            const f16x8 a1 = *(const f16x8*)(wA_off + (size_t)((ks * 2 + 1) * 64 + l) * 8);
            oa0 = __builtin_amdgcn_mfma_f32_16x16x32_f16(a0, bf, oa0, 0, 0, 0);
            oa1 = __builtin_amdgcn_mfma_f32_16x16x32_f16(a1, bf, oa1, 0, 0, 0);
        }
        #pragma unroll
        for (int reg = 0; reg < 4; ++reg) {
            const int c0 = cg * 4 + reg;
            offs[c0][slot] = oa0[reg] + offb[c0];
            const int c1 = c0 + 16;
            if (c1 < 18) offs[c1][slot] = oa1[reg] + offb[c1];
        }
    }
    __syncthreads();   // offs final; win read-only from here

    // ---- tap precompute (window covers full tap reach: 9 rows x 20 cols) ----
    int o00[9], o01[9], o10[9], o11[9];
    f16x2 hA[9], hB[9];
    unsigned okm = 0;
    #pragma unroll
    for (int t = 0; t < 9; ++t) {
        const int ky = t / 3, kx = t - ky * 3;
        const float dy = offs[2 * t][slot], dx = offs[2 * t + 1][slot];
        const float py  = (float)(row - 1 + ky) + dy;
        const float pxf = (float)(gpx - 1 + kx) + dx;
        const float y0f = floorf(py), x0f = floorf(pxf);
        const float wy = py - y0f, wx = pxf - x0f;
        const int y0 = (int)y0f, x0 = (int)x0f;
        const int y1 = y0 + 1, x1 = x0 + 1;
        const bool vy0 = (y0 >= 0) & (y0 < HH), vy1 = (y1 >= 0) & (y1 < HH);
        const bool vx0 = (x0 >= 0) & (x0 < WW), vx1 = (x1 >= 0) & (x1 < WW);
        hA[t][0] = (f16)((1.f - wy) * (1.f - wx) * (float)(vy0 & vx0));
        hA[t][1] = (f16)((1.f - wy) * wx         * (float)(vy0 & vx1));
        hB[t][0] = (f16)(wy * (1.f - wx)         * (float)(vy1 & vx0));
        hB[t][1] = (f16)(wy * wx                 * (float)(vy1 & vx1));
        const int cy0 = min(max(y0, 0), HH - 1), cy1 = min(max(y1, 0), HH - 1);
        const int cx0 = min(max(x0, 0), WW - 1), cx1 = min(max(x1, 0), WW - 1);
        const int s0 = cy0 - (r0 - 2), s1 = cy1 - (r0 - 2);
        const int u0 = cx0 - (px0 - 2), u1 = cx1 - (px0 - 2);
        const int ok = (s0 >= 0) & (s0 < R9) & (s1 >= 0) & (s1 < R9) &
                       (u0 >= 0) & (u0 < XW) & (u1 >= 0) & (u1 < XW);
        if (__all(ok)) okm |= (1u << t);
        const int s0c = min(max(s0, 0), R9 - 1), s1c = min(max(s1, 0), R9 - 1);
        const int u0c = min(max(u0, 0), XW - 1), u1c = min(max(u1, 0), XW - 1);
        o00[t] = ((s0c * XW + u0c) * 8 + (cg ^ ((u0c + s0c) & 7))) * 16;
        o01[t] = ((s0c * XW + u1c) * 8 + (cg ^ ((u1c + s0c) & 7))) * 16;
        o10[t] = ((s1c * XW + u0c) * 8 + (cg ^ ((u0c + s1c) & 7))) * 16;
        o11[t] = ((s1c * XW + u1c) * 8 + (cg ^ ((u1c + s1c) & 7))) * 16;
    }

    f32x4 acc0 = {0,0,0,0}, acc1 = {0,0,0,0}, acc2 = {0,0,0,0}, acc3 = {0,0,0,0};
    const f16* wbase = wA_def + (size_t)l * 8;

    if (okm == 0x1FFu) {
        // ---- FAST PATH: branch-free 18 clusters, gathers from LDS ----
        #pragma unroll
        for (int j = 0; j < 18; ++j) {
            const int t = j >> 1, fl = (j & 1) << 6;
            const f16x8 p00 = *(const f16x8*)(win + (o00[t] ^ fl));
            const f16x8 p01 = *(const f16x8*)(win + (o01[t] ^ fl));
            const f16x8 p10 = *(const f16x8*)(win + (o10[t] ^ fl));
            const f16x8 p11 = *(const f16x8*)(win + (o11[t] ^ fl));
            const f16x8 bf = combine4(p00, p01, p10, p11,
                                      hA[t][0], hA[t][1], hB[t][0], hB[t][1]);
            const f16* wa = wbase + (size_t)j * 2048;
            acc0 = __builtin_amdgcn_mfma_f32_16x16x32_f16(*(const f16x8*)(wa + 0 * 512), bf, acc0, 0, 0, 0);
            acc1 = __builtin_amdgcn_mfma_f32_16x16x32_f16(*(const f16x8*)(wa + 1 * 512), bf, acc1, 0, 0, 0);
            acc2 = __builtin_amdgcn_mfma_f32_16x16x32_f16(*(const f16x8*)(wa + 2 * 512), bf, acc2, 0, 0, 0);
            acc3 = __builtin_amdgcn_mfma_f32_16x16x32_f16(*(const f16x8*)(wa + 3 * 512), bf, acc3, 0, 0, 0);
        }
    } else {
        // ---- SLOW PATH: per-tap wave-uniform fallback to global gather ----
        #pragma unroll
        for (int t = 0; t < 9; ++t) {
            #pragma unroll
            for (int cpass = 0; cpass < 2; ++cpass) {
                const int flip = cpass << 6;
                f16x8 bf;
                if ((okm >> t) & 1) {
                    const f16x8 p00 = *(const f16x8*)(win + (o00[t] ^ flip));
                    const f16x8 p01 = *(const f16x8*)(win + (o01[t] ^ flip));
                    const f16x8 p10 = *(const f16x8*)(win + (o10[t] ^ flip));
                    const f16x8 p11 = *(const f16x8*)(win + (o11[t] ^ flip));
                    bf = combine4(p00, p01, p10, p11,
                                  hA[t][0], hA[t][1], hB[t][0], hB[t][1]);
                } else {
                    const int ky = t / 3, kx = t - ky * 3;
                    const float dy = offs[2 * t][slot], dx = offs[2 * t + 1][slot];
                    const float py  = (float)(row - 1 + ky) + dy;
                    const float pxf = (float)(gpx - 1 + kx) + dx;
                    const int y0 = (int)floorf(py), x0 = (int)floorf(pxf);
                    const int cy0 = min(max(y0, 0), HH - 1), cy1 = min(max(y0 + 1, 0), HH - 1);
                    const int cx0 = min(max(x0, 0), WW - 1), cx1 = min(max(x0 + 1, 0), WW - 1);
                    const int ch8 = cpass * 4 + cg;
                    const f16x8 p00 = *(const f16x8*)(xt + xt_idx(b, cy0, cx0) + ch8 * 8);
                    const f16x8 p01 = *(const f16x8*)(xt + xt_idx(b, cy0, cx1) + ch8 * 8);
                    const f16x8 p10 = *(const f16x8*)(xt + xt_idx(b, cy1, cx0) + ch8 * 8);
                    const f16x8 p11 = *(const f16x8*)(xt + xt_idx(b, cy1, cx1) + ch8 * 8);
                    bf = combine4(p00, p01, p10, p11,
                                  hA[t][0], hA[t][1], hB[t][0], hB[t][1]);
                }
                const f16* wa = wbase + (size_t)(t * 2 + cpass) * 2048;
                acc0 = __builtin_amdgcn_mfma_f32_16x16x32_f16(*(const f16x8*)(wa + 0 * 512), bf, acc0, 0, 0, 0);
                acc1 = __builtin_amdgcn_mfma_f32_16x16x32_f16(*(const f16x8*)(wa + 1 * 512), bf, acc1, 0, 0, 0);
                acc2 = __builtin_amdgcn_mfma_f32_16x16x32_f16(*(const f16x8*)(wa + 2 * 512), bf, acc2, 0, 0, 0);
                acc3 = __builtin_amdgcn_mfma_f32_16x16x32_f16(*(const f16x8*)(wa + 3 * 512), bf, acc3, 0, 0, 0);
            }
        }
    }

    // ---- epilogue ----
    #pragma unroll
    for (int mt = 0; mt < 4; ++mt) {
        const f32x4 a = (mt == 0) ? acc0 : (mt == 1) ? acc1 : (mt == 2) ? acc2 : acc3;
        #pragma unroll
        for (int reg = 0; reg < 4; ++reg) {
            const int o = mt * 16 + cg * 4 + reg;
            out[(((size_t)b * OO + o) * HH + row) * WW + gpx] = a[reg] + dbias[o];
        }
    }
}

extern "C" void kernel_launch(void* const* d_in, const int* in_sizes, int n_in,
                              void* d_out, int out_size, void* d_ws, size_t ws_size,
                              hipStream_t stream) {
    const float* x     = (const float*)d_in[0];
    const float* offw  = (const float*)d_in[1];
    const float* offb  = (const float*)d_in[2];
    const float* dw    = (const float*)d_in[3];
    const float* dbias = (const float*)d_in[4];
    float* out = (float*)d_out;

    const size_t XT_BYTES    = (size_t)BB * HH * WW * CC * sizeof(f16);   // 8 MiB
    const size_t WAOFF_BYTES = 36 * 64 * 8 * sizeof(f16);

    f16* xt     = (f16*)d_ws;
    f16* wa_off = (f16*)((char*)d_ws + XT_BYTES);
    f16* wa_def = (f16*)((char*)d_ws + XT_BYTES + WAOFF_BYTES);
    (void)ws_size; (void)in_sizes; (void)n_in; (void)out_size;

    prep_all<<<512 + 27, 256, 0, stream>>>(x, offw, dw, xt, wa_off, wa_def);
    deform_mfma<<<1024, 256, 0, stream>>>(xt, wa_off, offb, wa_def, dbias, out);
}